// Round 5
// baseline (5985.228 us; speedup 1.0000x reference)
//
#include <hip/hip_runtime.h>
#include <hip/hip_bf16.h>
#include <stdint.h>

// Problem dims (fixed): B=16, T=256, D=512, H=1024, L=512, V=32000
#define ENC_NB 64
#define DEC_NB 32
#define FLAG_STRIDE 16   // dwords -> one 64B line per flag (no false sharing)

typedef __attribute__((ext_vector_type(4))) float f32x4;
typedef __attribute__((ext_vector_type(4))) int   i32x4;
typedef __attribute__((ext_vector_type(8))) __bf16 bf16x8;

__device__ __forceinline__ float sigf(float x) { return 1.f / (1.f + __expf(-x)); }
__device__ __forceinline__ float tanhf_fast(float x) { return 1.f - 2.f / (__expf(2.f * x) + 1.f); }

__device__ __forceinline__ unsigned short f2bf(float f) {
    union { __hip_bfloat16 h; unsigned short u; } cv;
    cv.h = __float2bfloat16(f);
    return cv.u;
}

// coherent (agent-scope, cache-bypassing) 16B load as two 8B atomic loads
__device__ __forceinline__ bf16x8 loadc16(const unsigned short* p) {
    unsigned long long a = __hip_atomic_load((const unsigned long long*)p,
                                             __ATOMIC_RELAXED, __HIP_MEMORY_SCOPE_AGENT);
    unsigned long long b = __hip_atomic_load((const unsigned long long*)(p + 4),
                                             __ATOMIC_RELAXED, __HIP_MEMORY_SCOPE_AGENT);
    union { bf16x8 v; unsigned long long q[2]; } u;
    u.q[0] = a; u.q[1] = b;
    return u.v;
}
// coherent write-through 2B store
__device__ __forceinline__ void storec2(unsigned short* p, unsigned short v) {
    __hip_atomic_store(p, v, __ATOMIC_RELAXED, __HIP_MEMORY_SCOPE_AGENT);
}

// ---- flag barrier, fence-free: data is sc-coherent, so no wbl2/inv needed ----
__device__ __forceinline__ void flag_arrive(unsigned* flags, int bid, unsigned target, int tid) {
    asm volatile("s_waitcnt vmcnt(0)" ::: "memory");   // this wave's coherent stores committed
    __syncthreads();                                   // all waves did the waitcnt
    if (tid == 0)
        __hip_atomic_store(&flags[bid * FLAG_STRIDE], target,
                           __ATOMIC_RELAXED, __HIP_MEMORY_SCOPE_AGENT);
}
__device__ __forceinline__ void flag_wait(unsigned* flags, int nb, unsigned target, int tid) {
    if (tid < 64) {
        int idx = (tid < nb) ? tid : 0;
        long sp = 0;
        while (__hip_atomic_load(&flags[idx * FLAG_STRIDE],
                                 __ATOMIC_RELAXED, __HIP_MEMORY_SCOPE_AGENT) < target) {
            if (++sp > (1L << 24)) break;  // safety valve: wrong answer beats a hang
        }
    }
    __syncthreads();
    __builtin_amdgcn_sched_barrier(0);
    asm volatile("" ::: "memory");
}

// ---------------- init: zero flag words ----------------
__global__ void init_kernel(unsigned* flags) {
    int id = blockIdx.x * 256 + threadIdx.x;
    if (id < (ENC_NB + DEC_NB) * FLAG_STRIDE) flags[id] = 0u;
}

// ---------------- x (fp32 [B,T,D]) -> bf16 same layout ----------------
__global__ __launch_bounds__(256) void cvt_x(const float* __restrict__ x, unsigned short* __restrict__ xb) {
    int id = blockIdx.x * 256 + threadIdx.x;          // 524288 = 2M/4
    if (id >= 524288) return;
    f32x4 v = *(const f32x4*)(x + (size_t)id * 4);
    ushort4 r;
    r.x = f2bf(v.x); r.y = f2bf(v.y); r.z = f2bf(v.z); r.w = f2bf(v.w);
    *(ushort4*)(xb + (size_t)id * 4) = r;
}

// ---------------- encoder LSTM: MFMA, weights in registers, fence-free flag barrier ----------------
// 64 blocks x 256 thr. wave gw=bk*4+wv owns units u0=gw*4..u0+3, all 4 gates.
// col(n) = (n&3)*1024 + u0 + (n>>2), n = lane&15. A-frag: lane reads act[b=lane&15][kch..kch+8).
__global__ __launch_bounds__(256, 1) void enc_kernel(
        const float* __restrict__ Wih, const float* __restrict__ Whh,
        const float* __restrict__ bih, const float* __restrict__ bhh,
        const unsigned short* __restrict__ x_bf, unsigned short* h_bf /*2 x 16*1024*/,
        float* __restrict__ hT, unsigned* flags) {
    const int tid = threadIdx.x, bk = blockIdx.x;
    const int l = tid & 63, wv = tid >> 6;
    const int gw = bk * 4 + wv, u0 = gw * 4;
    const int n = l & 15;
    const int col = (n & 3) * 1024 + u0 + (n >> 2);
    const int kch = (l >> 4) * 8;                      // k offset within a 32-wide fragment
    // ---- one-time: weights -> registers (bf16), 48 fragments of K=32 ----
    bf16x8 wf[48];
    #pragma unroll
    for (int kk = 0; kk < 48; ++kk) {
        const float* src = (kk < 16) ? (Wih + (size_t)col * 512 + kk * 32 + kch)
                                     : (Whh + (size_t)col * 1024 + (kk - 16) * 32 + kch);
        f32x4 w0 = *(const f32x4*)src;
        f32x4 w1 = *(const f32x4*)(src + 4);
        union { bf16x8 v; unsigned short u[8]; } cv;
        cv.u[0] = f2bf(w0.x); cv.u[1] = f2bf(w0.y); cv.u[2] = f2bf(w0.z); cv.u[3] = f2bf(w0.w);
        cv.u[4] = f2bf(w1.x); cv.u[5] = f2bf(w1.y); cv.u[6] = f2bf(w1.z); cv.u[7] = f2bf(w1.w);
        wf[kk] = cv.v;
    }
    const float bias = bih[col] + bhh[col];
    float c0 = 0.f, c1 = 0.f, c2 = 0.f, c3 = 0.f;
    const int unit = u0 + (n >> 2);
    const bool b0 = (l & 1), b1 = (l & 2);
    const bool g0lane = ((l & 3) == 0);
    for (int t = 0; t < 256; ++t) {
        // ---- x-part first: independent of h_{t-1}, overlaps the barrier wait ----
        f32x4 acc0 = {0.f, 0.f, 0.f, 0.f}, acc1 = {0.f, 0.f, 0.f, 0.f};
        const unsigned short* xrow = x_bf + ((size_t)(l & 15) * 256 + t) * 512 + kch;
        #pragma unroll
        for (int kk = 0; kk < 16; ++kk) {
            bf16x8 a = *(const bf16x8*)(xrow + kk * 32);
            acc0 = __builtin_amdgcn_mfma_f32_16x16x32_bf16(a, wf[kk], acc0, 0, 0, 0);
        }
        if (t > 0) {
            flag_wait(flags, ENC_NB, (unsigned)t, tid);
            const unsigned short* hrow = h_bf + (t & 1) * 16384 + (l & 15) * 1024 + kch;
            // issue ALL coherent loads first (program order: loads -> MFMAs) so they pipeline
            bf16x8 ha[32];
            #pragma unroll
            for (int kk = 0; kk < 32; ++kk) ha[kk] = loadc16(hrow + kk * 32);
            #pragma unroll
            for (int kk = 0; kk < 16; ++kk) {          // two independent MFMA chains
                acc0 = __builtin_amdgcn_mfma_f32_16x16x32_bf16(ha[kk],      wf[16 + kk], acc0, 0, 0, 0);
                acc1 = __builtin_amdgcn_mfma_f32_16x16x32_bf16(ha[kk + 16], wf[32 + kk], acc1, 0, 0, 0);
            }
        }
        unsigned short* hw = h_bf + ((t + 1) & 1) * 16384;
        #pragma unroll
        for (int j = 0; j < 4; ++j) {
            float v   = acc0[j] + acc1[j] + bias;
            float vx1 = __shfl_xor(v, 1, 64);
            float vx2 = __shfl_xor(v, 2, 64);
            float vx3 = __shfl_xor(vx1, 2, 64);
            float iv = b1 ? (b0 ? vx3 : vx2) : (b0 ? vx1 : v);
            float fv = b1 ? (b0 ? vx2 : vx3) : (b0 ? v   : vx1);
            float gv = b1 ? (b0 ? vx1 : v  ) : (b0 ? vx3 : vx2);
            float ov = b1 ? (b0 ? v   : vx1) : (b0 ? vx2 : vx3);
            float cj = (j == 0) ? c0 : (j == 1) ? c1 : (j == 2) ? c2 : c3;
            float cn = sigf(fv) * cj + sigf(iv) * tanhf_fast(gv);
            if (j == 0) c0 = cn; else if (j == 1) c1 = cn; else if (j == 2) c2 = cn; else c3 = cn;
            float h = sigf(ov) * tanhf_fast(cn);
            if (g0lane) {
                int bat = (l >> 4) * 4 + j;
                storec2(hw + bat * 1024 + unit, f2bf(h));
                if (t == 255) hT[bat * 1024 + unit] = h;
            }
        }
        flag_arrive(flags, bk, (unsigned)(t + 1), tid);
    }
}

// ---------------- mu / logvar / z (+ tail outputs, + z_bf for decoder h0) ----------------
__global__ __launch_bounds__(256) void mlz_kernel(
        const float* __restrict__ hT, const float* __restrict__ Wmu, const float* __restrict__ bmu,
        const float* __restrict__ Wlv, const float* __restrict__ blv, const float* __restrict__ eps,
        unsigned short* __restrict__ z_bf, float* __restrict__ out_tail) {
    int id = blockIdx.x * 256 + threadIdx.x;   // 8192 = b*512 + l
    int l = id & 511, b = id >> 9;
    const float* hb = hT + b * 1024;
    const float* wm = Wmu + (size_t)l * 1024;
    const float* wl = Wlv + (size_t)l * 1024;
    float am = 0.f, al = 0.f;
    for (int k = 0; k < 256; ++k) {
        f32x4 h4 = *(const f32x4*)(hb + k * 4);
        f32x4 m4 = *(const f32x4*)(wm + k * 4);
        f32x4 l4 = *(const f32x4*)(wl + k * 4);
        am += m4.x * h4.x + m4.y * h4.y + m4.z * h4.z + m4.w * h4.w;
        al += l4.x * h4.x + l4.y * h4.y + l4.z * h4.z + l4.w * h4.w;
    }
    float mu = fmaxf(am + bmu[l], 0.f);
    float lv = fmaxf(al + blv[l], 0.f);
    float z  = eps[id] * __expf(0.5f * lv) + mu;
    z_bf[id] = f2bf(z);
    out_tail[id] = z;                 // z4
    out_tail[8192 + id] = mu;         // mu4
    out_tail[16384 + id] = lv;        // lv4
}

// ---------------- decoder LSTM: MFMA, weights in registers; h stream IS ys_bf ----------------
// 32 blocks x 256 thr. wave gw=bk*4+wv (0..127) owns units u0=gw*4..+3. col(n)=(n&3)*512+u0+(n>>2).
__global__ __launch_bounds__(256, 1) void dec_kernel(
        const float* __restrict__ Wih, const float* __restrict__ Whh,
        const float* __restrict__ bih, const float* __restrict__ bhh,
        const unsigned short* __restrict__ x_bf, const unsigned short* __restrict__ z_bf,
        unsigned short* __restrict__ ys_bf, unsigned* flags) {
    const int tid = threadIdx.x, bk = blockIdx.x;
    const int l = tid & 63, wv = tid >> 6;
    const int gw = bk * 4 + wv, u0 = gw * 4;
    const int n = l & 15;
    const int col = (n & 3) * 512 + u0 + (n >> 2);
    const int kch = (l >> 4) * 8;
    bf16x8 wf[32];
    #pragma unroll
    for (int kk = 0; kk < 32; ++kk) {
        const float* src = (kk < 16) ? (Wih + (size_t)col * 512 + kk * 32 + kch)
                                     : (Whh + (size_t)col * 512 + (kk - 16) * 32 + kch);
        f32x4 w0 = *(const f32x4*)src;
        f32x4 w1 = *(const f32x4*)(src + 4);
        union { bf16x8 v; unsigned short u[8]; } cv;
        cv.u[0] = f2bf(w0.x); cv.u[1] = f2bf(w0.y); cv.u[2] = f2bf(w0.z); cv.u[3] = f2bf(w0.w);
        cv.u[4] = f2bf(w1.x); cv.u[5] = f2bf(w1.y); cv.u[6] = f2bf(w1.z); cv.u[7] = f2bf(w1.w);
        wf[kk] = cv.v;
    }
    const float bias = bih[col] + bhh[col];
    float c0 = 0.f, c1 = 0.f, c2 = 0.f, c3 = 0.f;
    const int unit = u0 + (n >> 2);
    const bool b0 = (l & 1), b1 = (l & 2);
    const bool g0lane = ((l & 3) == 0);
    for (int t = 0; t < 256; ++t) {
        f32x4 acc0 = {0.f, 0.f, 0.f, 0.f}, acc1 = {0.f, 0.f, 0.f, 0.f};
        if (t > 0) {                                    // x-part (dec_in[t] = x[t-1]); overlaps wait
            const unsigned short* xrow = x_bf + ((size_t)(l & 15) * 256 + (t - 1)) * 512 + kch;
            #pragma unroll
            for (int kk = 0; kk < 16; ++kk) {
                bf16x8 a = *(const bf16x8*)(xrow + kk * 32);
                acc0 = __builtin_amdgcn_mfma_f32_16x16x32_bf16(a, wf[kk], acc0, 0, 0, 0);
            }
            flag_wait(flags, DEC_NB, (unsigned)t, tid);
        }
        const unsigned short* hrow = (t == 0)
            ? (z_bf + (l & 15) * 512 + kch)
            : (ys_bf + ((size_t)(l & 15) * 256 + (t - 1)) * 512 + kch);
        bf16x8 ha[16];
        #pragma unroll
        for (int kk = 0; kk < 16; ++kk) ha[kk] = loadc16(hrow + kk * 32);
        #pragma unroll
        for (int kk = 0; kk < 8; ++kk) {                // two independent MFMA chains
            acc0 = __builtin_amdgcn_mfma_f32_16x16x32_bf16(ha[kk],     wf[16 + kk], acc0, 0, 0, 0);
            acc1 = __builtin_amdgcn_mfma_f32_16x16x32_bf16(ha[kk + 8], wf[24 + kk], acc1, 0, 0, 0);
        }
        #pragma unroll
        for (int j = 0; j < 4; ++j) {
            float v   = acc0[j] + acc1[j] + bias;
            float vx1 = __shfl_xor(v, 1, 64);
            float vx2 = __shfl_xor(v, 2, 64);
            float vx3 = __shfl_xor(vx1, 2, 64);
            float iv = b1 ? (b0 ? vx3 : vx2) : (b0 ? vx1 : v);
            float fv = b1 ? (b0 ? vx2 : vx3) : (b0 ? v   : vx1);
            float gv = b1 ? (b0 ? vx1 : v  ) : (b0 ? vx3 : vx2);
            float ov = b1 ? (b0 ? v   : vx1) : (b0 ? vx2 : vx3);
            float cj = (j == 0) ? c0 : (j == 1) ? c1 : (j == 2) ? c2 : c3;
            float cn = sigf(fv) * cj + sigf(iv) * tanhf_fast(gv);
            if (j == 0) c0 = cn; else if (j == 1) c1 = cn; else if (j == 2) c2 = cn; else c3 = cn;
            float h = sigf(ov) * tanhf_fast(cn);
            if (g0lane) {
                int bat = (l >> 4) * 4 + j;
                storec2(ys_bf + ((size_t)bat * 256 + t) * 512 + unit, f2bf(h));
            }
        }
        flag_arrive(flags, bk, (unsigned)(t + 1), tid);
    }
}

// ---------------- logits GEMM: [4096,512]x[512,32000], bf16 MFMA 16x16x32, 128x128 tile ----------------
// W (Wout) is fp32 [32000,512]; converted to bf16 on the fly while staging to LDS.
__global__ __launch_bounds__(256) void gemm_logits(
        const unsigned short* __restrict__ A, const float* __restrict__ W,
        const float* __restrict__ bout, float* __restrict__ out) {
    __shared__ __align__(16) unsigned short lA[128 * 32];
    __shared__ __align__(16) unsigned short lB[128 * 32];
    const int tid = threadIdx.x, bid = blockIdx.x;
    const int mt = bid & 31, nt = bid >> 5;           // m fastest: consecutive blocks share W-panel
    const int m0 = mt * 128, n0 = nt * 128;
    const int lane = tid & 63, wv = tid >> 6;
    const int wm = wv >> 1, wn = wv & 1;
    const int sr = tid >> 2, sc = (tid & 3) * 8;      // sr 0..63, sc in shorts (16B chunks)
    const int fr = lane & 15, kc = (lane >> 4) * 8;
    f32x4 acc[4][4];
    #pragma unroll
    for (int i = 0; i < 4; ++i)
        #pragma unroll
        for (int j = 0; j < 4; ++j) acc[i][j] = f32x4{0.f, 0.f, 0.f, 0.f};
    for (int k0 = 0; k0 < 512; k0 += 32) {
        __syncthreads();
        #pragma unroll
        for (int r0 = 0; r0 < 128; r0 += 64) {
            int r = sr + r0;
            *(i32x4*)(lA + r * 32 + sc) = *(const i32x4*)(A + (size_t)(m0 + r) * 512 + k0 + sc);
            f32x4 w0 = *(const f32x4*)(W + (size_t)(n0 + r) * 512 + k0 + sc);
            f32x4 w1 = *(const f32x4*)(W + (size_t)(n0 + r) * 512 + k0 + sc + 4);
            union { bf16x8 v; unsigned short u[8]; } cv;
            cv.u[0] = f2bf(w0.x); cv.u[1] = f2bf(w0.y); cv.u[2] = f2bf(w0.z); cv.u[3] = f2bf(w0.w);
            cv.u[4] = f2bf(w1.x); cv.u[5] = f2bf(w1.y); cv.u[6] = f2bf(w1.z); cv.u[7] = f2bf(w1.w);
            *(bf16x8*)(lB + r * 32 + sc) = cv.v;
        }
        __syncthreads();
        bf16x8 af[4], bfr[4];
        #pragma unroll
        for (int mi = 0; mi < 4; ++mi)
            af[mi] = *(const bf16x8*)(lA + (wm * 64 + mi * 16 + fr) * 32 + kc);
        #pragma unroll
        for (int ni = 0; ni < 4; ++ni)
            bfr[ni] = *(const bf16x8*)(lB + (wn * 64 + ni * 16 + fr) * 32 + kc);
        #pragma unroll
        for (int mi = 0; mi < 4; ++mi)
            #pragma unroll
            for (int ni = 0; ni < 4; ++ni)
                acc[mi][ni] = __builtin_amdgcn_mfma_f32_16x16x32_bf16(af[mi], bfr[ni], acc[mi][ni], 0, 0, 0);
    }
    const int orow = (lane >> 4) * 4;
    #pragma unroll
    for (int mi = 0; mi < 4; ++mi) {
        #pragma unroll
        for (int ni = 0; ni < 4; ++ni) {
            int gm = m0 + wm * 64 + mi * 16 + orow;
            int gn = n0 + wn * 64 + ni * 16 + fr;
            float bo = bout[gn];
            #pragma unroll
            for (int j = 0; j < 4; ++j)
                out[(size_t)(gm + j) * 32000 + gn] = acc[mi][ni][j] + bo;
        }
    }
}

// ---------------- row softmax in-place (LDS row buffer: 1 read + 1 write of HBM) ----------------
__global__ __launch_bounds__(512) void softmax_kernel(float* __restrict__ out) {
    __shared__ __align__(16) float row[32000];
    __shared__ float red[8];
    const int tid = threadIdx.x;
    float* p = out + (size_t)blockIdx.x * 32000;
    float mx = -3.4e38f;
    for (int c = tid; c < 8000; c += 512) {
        f32x4 v = *(const f32x4*)(p + c * 4);
        *(f32x4*)(row + c * 4) = v;
        mx = fmaxf(mx, fmaxf(fmaxf(v.x, v.y), fmaxf(v.z, v.w)));
    }
    #pragma unroll
    for (int o = 32; o; o >>= 1) mx = fmaxf(mx, __shfl_xor(mx, o, 64));
    if ((tid & 63) == 0) red[tid >> 6] = mx;
    __syncthreads();
    if (tid == 0) {
        float m = red[0];
        for (int i = 1; i < 8; ++i) m = fmaxf(m, red[i]);
        red[0] = m;
    }
    __syncthreads();
    mx = red[0];
    __syncthreads();
    float s = 0.f;
    for (int c = tid; c < 8000; c += 512) {
        f32x4 v = *(f32x4*)(row + c * 4);
        v.x = __expf(v.x - mx); v.y = __expf(v.y - mx);
        v.z = __expf(v.z - mx); v.w = __expf(v.w - mx);
        *(f32x4*)(row + c * 4) = v;
        s += v.x + v.y + v.z + v.w;
    }
    #pragma unroll
    for (int o = 32; o; o >>= 1) s += __shfl_xor(s, o, 64);
    if ((tid & 63) == 0) red[tid >> 6] = s;
    __syncthreads();
    if (tid == 0) {
        float t2 = 0.f;
        for (int i = 0; i < 8; ++i) t2 += red[i];
        red[0] = t2;
    }
    __syncthreads();
    float inv = 1.f / red[0];
    for (int c = tid; c < 8000; c += 512) {
        f32x4 v = *(f32x4*)(row + c * 4);
        v.x *= inv; v.y *= inv; v.z *= inv; v.w *= inv;
        *(f32x4*)(p + c * 4) = v;
    }
}

extern "C" void kernel_launch(void* const* d_in, const int* in_sizes, int n_in,
                              void* d_out, int out_size, void* d_ws, size_t ws_size,
                              hipStream_t stream) {
    (void)in_sizes; (void)n_in; (void)out_size; (void)ws_size;
    const float* x    = (const float*)d_in[0];
    const float* eps  = (const float*)d_in[1];
    const float* eWih = (const float*)d_in[2];
    const float* eWhh = (const float*)d_in[3];
    const float* ebih = (const float*)d_in[4];
    const float* ebhh = (const float*)d_in[5];
    const float* Wmu  = (const float*)d_in[6];
    const float* bmu  = (const float*)d_in[7];
    const float* Wlv  = (const float*)d_in[8];
    const float* blv  = (const float*)d_in[9];
    const float* dWih = (const float*)d_in[10];
    const float* dWhh = (const float*)d_in[11];
    const float* dbih = (const float*)d_in[12];
    const float* dbhh = (const float*)d_in[13];
    const float* Wout = (const float*)d_in[14];
    const float* bout = (const float*)d_in[15];
    float* out = (float*)d_out;

    // workspace layout (bytes):
    char* ws = (char*)d_ws;
    unsigned* flags_e    = (unsigned*)ws;                         // 64*16*4 = 4 KB
    unsigned* flags_d    = (unsigned*)(ws + 4096);                // 32*16*4 = 2 KB
    unsigned short* x_bf = (unsigned short*)(ws + 8192);          // 16*256*512*2 = 4 MB
    unsigned short* ysbf = x_bf + (size_t)16 * 256 * 512;         // 4096*512*2 = 4 MB
    unsigned short* h_bf = ysbf + (size_t)4096 * 512;             // 2 * 16*1024 * 2B = 64 KB
    unsigned short* z_bf = h_bf + 2 * 16 * 1024;                  // 16*512*2 = 16 KB
    float* hT            = (float*)(z_bf + 16 * 512);             // 16*1024*4 = 64 KB

    hipLaunchKernelGGL(init_kernel, dim3(8), dim3(256), 0, stream, flags_e);
    hipLaunchKernelGGL(cvt_x, dim3(2048), dim3(256), 0, stream, x, x_bf);
    hipLaunchKernelGGL(enc_kernel, dim3(ENC_NB), dim3(256), 0, stream,
                       eWih, eWhh, ebih, ebhh, x_bf, h_bf, hT, flags_e);
    hipLaunchKernelGGL(mlz_kernel, dim3(32), dim3(256), 0, stream,
                       hT, Wmu, bmu, Wlv, blv, eps, z_bf, out + 131072000);
    hipLaunchKernelGGL(dec_kernel, dim3(DEC_NB), dim3(256), 0, stream,
                       dWih, dWhh, dbih, dbhh, x_bf, z_bf, ysbf, flags_d);
    hipLaunchKernelGGL(gemm_logits, dim3(8000), dim3(256), 0, stream, ysbf, Wout, bout, out);
    hipLaunchKernelGGL(softmax_kernel, dim3(4096), dim3(512), 0, stream, out);
}

// Round 6
// 4355.196 us; speedup vs baseline: 1.3743x; 1.3743x over previous
//
#include <hip/hip_runtime.h>
#include <hip/hip_bf16.h>
#include <stdint.h>

// Problem dims (fixed): B=16, T=256, D=512, H=1024, L=512, V=32000
#define ENC_NB 64
#define DEC_NB 32
#define FLAG_STRIDE 16   // dwords -> one 64B line per flag (no false sharing)

typedef __attribute__((ext_vector_type(4))) float f32x4;
typedef __attribute__((ext_vector_type(4))) int   i32x4;
typedef __attribute__((ext_vector_type(8))) __bf16 bf16x8;

__device__ __forceinline__ float sigf(float x) { return 1.f / (1.f + __expf(-x)); }
__device__ __forceinline__ float tanhf_fast(float x) { return 1.f - 2.f / (__expf(2.f * x) + 1.f); }

__device__ __forceinline__ unsigned short f2bf(float f) {
    union { __hip_bfloat16 h; unsigned short u; } cv;
    cv.h = __float2bfloat16(f);
    return cv.u;
}

// write-through (agent-coherent) 2B store: data lands at the coherent point (L3),
// so release needs no L2 writeback and consumers' fresh-address loads see it.
__device__ __forceinline__ void storec2(unsigned short* p, unsigned short v) {
    __hip_atomic_store(p, v, __ATOMIC_RELAXED, __HIP_MEMORY_SCOPE_AGENT);
}

// ---- flag barrier, fence-free ----
// arrive: all data stores are write-through; vmcnt(0) = committed; then one flag store.
__device__ __forceinline__ void flag_arrive(unsigned* flags, int bid, unsigned target, int tid) {
    asm volatile("s_waitcnt vmcnt(0)" ::: "memory");   // this wave's stores committed to L3
    __syncthreads();                                   // all waves did the waitcnt
    if (tid == 0)
        __hip_atomic_store(&flags[bid * FLAG_STRIDE], target,
                           __ATOMIC_RELAXED, __HIP_MEMORY_SCOPE_AGENT);
}
// wait: wave 0 polls all flags in parallel (lane i watches flag i), L1/L2-bypassing loads.
__device__ __forceinline__ void flag_wait(unsigned* flags, int nb, unsigned target, int tid) {
    if (tid < 64) {
        int idx = (tid < nb) ? tid : 0;
        long sp = 0;
        while (__hip_atomic_load(&flags[idx * FLAG_STRIDE],
                                 __ATOMIC_RELAXED, __HIP_MEMORY_SCOPE_AGENT) < target) {
            if (++sp > (1L << 24)) break;  // safety valve: wrong answer beats a hang
        }
    }
    __syncthreads();
    __builtin_amdgcn_sched_barrier(0);                 // keep h loads below the wait
    asm volatile("" ::: "memory");
}

// ---------------- init: zero flag words ----------------
__global__ void init_kernel(unsigned* flags) {
    int id = blockIdx.x * 256 + threadIdx.x;
    if (id < (ENC_NB + DEC_NB) * FLAG_STRIDE) flags[id] = 0u;
}

// ---------------- x (fp32 [B,T,D]) -> bf16 same layout ----------------
__global__ __launch_bounds__(256) void cvt_x(const float* __restrict__ x, unsigned short* __restrict__ xb) {
    int id = blockIdx.x * 256 + threadIdx.x;          // 524288 = 2M/4
    if (id >= 524288) return;
    f32x4 v = *(const f32x4*)(x + (size_t)id * 4);
    ushort4 r;
    r.x = f2bf(v.x); r.y = f2bf(v.y); r.z = f2bf(v.z); r.w = f2bf(v.w);
    *(ushort4*)(xb + (size_t)id * 4) = r;
}

// ---------------- encoder LSTM: MFMA, weights in registers, ring-buffered h ----------------
// 64 blocks x 256 thr. wave gw=bk*4+wv owns units u0=gw*4..u0+3, all 4 gates.
// col(n) = (n&3)*1024 + u0 + (n>>2), n = lane&15. A-frag: lane reads act[b=lane&15][kch..kch+8).
// h_ring[s] (s=0..255) holds h after step s; step t reads slot t-1 (fresh address -> L2 can't be stale).
__global__ __launch_bounds__(256, 1) void enc_kernel(
        const float* __restrict__ Wih, const float* __restrict__ Whh,
        const float* __restrict__ bih, const float* __restrict__ bhh,
        const unsigned short* __restrict__ x_bf, unsigned short* h_ring /*256 x 16*1024*/,
        float* __restrict__ hT, unsigned* flags) {
    const int tid = threadIdx.x, bk = blockIdx.x;
    const int l = tid & 63, wv = tid >> 6;
    const int gw = bk * 4 + wv, u0 = gw * 4;
    const int n = l & 15;
    const int col = (n & 3) * 1024 + u0 + (n >> 2);
    const int kch = (l >> 4) * 8;                      // k offset within a 32-wide fragment
    // ---- one-time: weights -> registers (bf16), 48 fragments of K=32 ----
    bf16x8 wf[48];
    #pragma unroll
    for (int kk = 0; kk < 48; ++kk) {
        const float* src = (kk < 16) ? (Wih + (size_t)col * 512 + kk * 32 + kch)
                                     : (Whh + (size_t)col * 1024 + (kk - 16) * 32 + kch);
        f32x4 w0 = *(const f32x4*)src;
        f32x4 w1 = *(const f32x4*)(src + 4);
        union { bf16x8 v; unsigned short u[8]; } cv;
        cv.u[0] = f2bf(w0.x); cv.u[1] = f2bf(w0.y); cv.u[2] = f2bf(w0.z); cv.u[3] = f2bf(w0.w);
        cv.u[4] = f2bf(w1.x); cv.u[5] = f2bf(w1.y); cv.u[6] = f2bf(w1.z); cv.u[7] = f2bf(w1.w);
        wf[kk] = cv.v;
    }
    const float bias = bih[col] + bhh[col];
    float c0 = 0.f, c1 = 0.f, c2 = 0.f, c3 = 0.f;
    const int unit = u0 + (n >> 2);
    const bool b0 = (l & 1), b1 = (l & 2);
    const bool g0lane = ((l & 3) == 0);
    for (int t = 0; t < 256; ++t) {
        // ---- x-part first: independent of h_{t-1}, overlaps the barrier wait ----
        f32x4 acc0 = {0.f, 0.f, 0.f, 0.f}, acc1 = {0.f, 0.f, 0.f, 0.f};
        const unsigned short* xrow = x_bf + ((size_t)(l & 15) * 256 + t) * 512 + kch;
        #pragma unroll
        for (int kk = 0; kk < 16; ++kk) {
            bf16x8 a = *(const bf16x8*)(xrow + kk * 32);
            acc0 = __builtin_amdgcn_mfma_f32_16x16x32_bf16(a, wf[kk], acc0, 0, 0, 0);
        }
        if (t > 0) {
            flag_wait(flags, ENC_NB, (unsigned)t, tid);
            // plain cached loads from a never-before-read ring slot (L2 miss -> fresh L3 data)
            const unsigned short* hrow = h_ring + (size_t)(t - 1) * 16384 + (l & 15) * 1024 + kch;
            bf16x8 ha[32];
            #pragma unroll
            for (int kk = 0; kk < 32; ++kk) ha[kk] = *(const bf16x8*)(hrow + kk * 32);
            #pragma unroll
            for (int kk = 0; kk < 16; ++kk) {          // two independent MFMA chains
                acc0 = __builtin_amdgcn_mfma_f32_16x16x32_bf16(ha[kk],      wf[16 + kk], acc0, 0, 0, 0);
                acc1 = __builtin_amdgcn_mfma_f32_16x16x32_bf16(ha[kk + 16], wf[32 + kk], acc1, 0, 0, 0);
            }
        }
        unsigned short* hw = h_ring + (size_t)t * 16384;
        #pragma unroll
        for (int j = 0; j < 4; ++j) {
            float v   = acc0[j] + acc1[j] + bias;
            float vx1 = __shfl_xor(v, 1, 64);
            float vx2 = __shfl_xor(v, 2, 64);
            float vx3 = __shfl_xor(vx1, 2, 64);
            float iv = b1 ? (b0 ? vx3 : vx2) : (b0 ? vx1 : v);
            float fv = b1 ? (b0 ? vx2 : vx3) : (b0 ? v   : vx1);
            float gv = b1 ? (b0 ? vx1 : v  ) : (b0 ? vx3 : vx2);
            float ov = b1 ? (b0 ? v   : vx1) : (b0 ? vx2 : vx3);
            float cj = (j == 0) ? c0 : (j == 1) ? c1 : (j == 2) ? c2 : c3;
            float cn = sigf(fv) * cj + sigf(iv) * tanhf_fast(gv);
            if (j == 0) c0 = cn; else if (j == 1) c1 = cn; else if (j == 2) c2 = cn; else c3 = cn;
            float h = sigf(ov) * tanhf_fast(cn);
            if (g0lane) {
                int bat = (l >> 4) * 4 + j;
                storec2(hw + bat * 1024 + unit, f2bf(h));   // write-through to coherent point
                if (t == 255) hT[bat * 1024 + unit] = h;    // plain (next-dispatch consumer)
            }
        }
        flag_arrive(flags, bk, (unsigned)(t + 1), tid);
    }
}

// ---------------- mu / logvar / z (+ tail outputs, + z_bf for decoder h0) ----------------
__global__ __launch_bounds__(256) void mlz_kernel(
        const float* __restrict__ hT, const float* __restrict__ Wmu, const float* __restrict__ bmu,
        const float* __restrict__ Wlv, const float* __restrict__ blv, const float* __restrict__ eps,
        unsigned short* __restrict__ z_bf, float* __restrict__ out_tail) {
    int id = blockIdx.x * 256 + threadIdx.x;   // 8192 = b*512 + l
    int l = id & 511, b = id >> 9;
    const float* hb = hT + b * 1024;
    const float* wm = Wmu + (size_t)l * 1024;
    const float* wl = Wlv + (size_t)l * 1024;
    float am = 0.f, al = 0.f;
    for (int k = 0; k < 256; ++k) {
        f32x4 h4 = *(const f32x4*)(hb + k * 4);
        f32x4 m4 = *(const f32x4*)(wm + k * 4);
        f32x4 l4 = *(const f32x4*)(wl + k * 4);
        am += m4.x * h4.x + m4.y * h4.y + m4.z * h4.z + m4.w * h4.w;
        al += l4.x * h4.x + l4.y * h4.y + l4.z * h4.z + l4.w * h4.w;
    }
    float mu = fmaxf(am + bmu[l], 0.f);
    float lv = fmaxf(al + blv[l], 0.f);
    float z  = eps[id] * __expf(0.5f * lv) + mu;
    z_bf[id] = f2bf(z);
    out_tail[id] = z;                 // z4
    out_tail[8192 + id] = mu;         // mu4
    out_tail[16384 + id] = lv;        // lv4
}

// ---------------- decoder LSTM: MFMA, weights in registers; ys IS the (time-indexed) h ring ----------------
// 32 blocks x 256 thr. wave gw=bk*4+wv (0..127) owns units u0=gw*4..+3. col(n)=(n&3)*512+u0+(n>>2).
__global__ __launch_bounds__(256, 1) void dec_kernel(
        const float* __restrict__ Wih, const float* __restrict__ Whh,
        const float* __restrict__ bih, const float* __restrict__ bhh,
        const unsigned short* __restrict__ x_bf, const unsigned short* __restrict__ z_bf,
        unsigned short* __restrict__ ys_bf, unsigned* flags) {
    const int tid = threadIdx.x, bk = blockIdx.x;
    const int l = tid & 63, wv = tid >> 6;
    const int gw = bk * 4 + wv, u0 = gw * 4;
    const int n = l & 15;
    const int col = (n & 3) * 512 + u0 + (n >> 2);
    const int kch = (l >> 4) * 8;
    bf16x8 wf[32];
    #pragma unroll
    for (int kk = 0; kk < 32; ++kk) {
        const float* src = (kk < 16) ? (Wih + (size_t)col * 512 + kk * 32 + kch)
                                     : (Whh + (size_t)col * 512 + (kk - 16) * 32 + kch);
        f32x4 w0 = *(const f32x4*)src;
        f32x4 w1 = *(const f32x4*)(src + 4);
        union { bf16x8 v; unsigned short u[8]; } cv;
        cv.u[0] = f2bf(w0.x); cv.u[1] = f2bf(w0.y); cv.u[2] = f2bf(w0.z); cv.u[3] = f2bf(w0.w);
        cv.u[4] = f2bf(w1.x); cv.u[5] = f2bf(w1.y); cv.u[6] = f2bf(w1.z); cv.u[7] = f2bf(w1.w);
        wf[kk] = cv.v;
    }
    const float bias = bih[col] + bhh[col];
    float c0 = 0.f, c1 = 0.f, c2 = 0.f, c3 = 0.f;
    const int unit = u0 + (n >> 2);
    const bool b0 = (l & 1), b1 = (l & 2);
    const bool g0lane = ((l & 3) == 0);
    for (int t = 0; t < 256; ++t) {
        f32x4 acc0 = {0.f, 0.f, 0.f, 0.f}, acc1 = {0.f, 0.f, 0.f, 0.f};
        if (t > 0) {                                    // x-part (dec_in[t] = x[t-1]); overlaps wait
            const unsigned short* xrow = x_bf + ((size_t)(l & 15) * 256 + (t - 1)) * 512 + kch;
            #pragma unroll
            for (int kk = 0; kk < 16; ++kk) {
                bf16x8 a = *(const bf16x8*)(xrow + kk * 32);
                acc0 = __builtin_amdgcn_mfma_f32_16x16x32_bf16(a, wf[kk], acc0, 0, 0, 0);
            }
            flag_wait(flags, DEC_NB, (unsigned)t, tid);
        }
        const unsigned short* hrow = (t == 0)
            ? (z_bf + (l & 15) * 512 + kch)
            : (ys_bf + ((size_t)(l & 15) * 256 + (t - 1)) * 512 + kch);
        bf16x8 ha[16];
        #pragma unroll
        for (int kk = 0; kk < 16; ++kk) ha[kk] = *(const bf16x8*)(hrow + kk * 32);
        #pragma unroll
        for (int kk = 0; kk < 8; ++kk) {                // two independent MFMA chains
            acc0 = __builtin_amdgcn_mfma_f32_16x16x32_bf16(ha[kk],     wf[16 + kk], acc0, 0, 0, 0);
            acc1 = __builtin_amdgcn_mfma_f32_16x16x32_bf16(ha[kk + 8], wf[24 + kk], acc1, 0, 0, 0);
        }
        #pragma unroll
        for (int j = 0; j < 4; ++j) {
            float v   = acc0[j] + acc1[j] + bias;
            float vx1 = __shfl_xor(v, 1, 64);
            float vx2 = __shfl_xor(v, 2, 64);
            float vx3 = __shfl_xor(vx1, 2, 64);
            float iv = b1 ? (b0 ? vx3 : vx2) : (b0 ? vx1 : v);
            float fv = b1 ? (b0 ? vx2 : vx3) : (b0 ? v   : vx1);
            float gv = b1 ? (b0 ? vx1 : v  ) : (b0 ? vx3 : vx2);
            float ov = b1 ? (b0 ? v   : vx1) : (b0 ? vx2 : vx3);
            float cj = (j == 0) ? c0 : (j == 1) ? c1 : (j == 2) ? c2 : c3;
            float cn = sigf(fv) * cj + sigf(iv) * tanhf_fast(gv);
            if (j == 0) c0 = cn; else if (j == 1) c1 = cn; else if (j == 2) c2 = cn; else c3 = cn;
            float h = sigf(ov) * tanhf_fast(cn);
            if (g0lane) {
                int bat = (l >> 4) * 4 + j;
                storec2(ys_bf + ((size_t)bat * 256 + t) * 512 + unit, f2bf(h));
            }
        }
        flag_arrive(flags, bk, (unsigned)(t + 1), tid);
    }
}

// ---------------- logits GEMM: [4096,512]x[512,32000], bf16 MFMA 16x16x32, 128x128 tile ----------------
// W (Wout) is fp32 [32000,512]; converted to bf16 on the fly while staging to LDS.
__global__ __launch_bounds__(256) void gemm_logits(
        const unsigned short* __restrict__ A, const float* __restrict__ W,
        const float* __restrict__ bout, float* __restrict__ out) {
    __shared__ __align__(16) unsigned short lA[128 * 32];
    __shared__ __align__(16) unsigned short lB[128 * 32];
    const int tid = threadIdx.x, bid = blockIdx.x;
    const int mt = bid & 31, nt = bid >> 5;           // m fastest: consecutive blocks share W-panel
    const int m0 = mt * 128, n0 = nt * 128;
    const int lane = tid & 63, wv = tid >> 6;
    const int wm = wv >> 1, wn = wv & 1;
    const int sr = tid >> 2, sc = (tid & 3) * 8;      // sr 0..63, sc in shorts (16B chunks)
    const int fr = lane & 15, kc = (lane >> 4) * 8;
    f32x4 acc[4][4];
    #pragma unroll
    for (int i = 0; i < 4; ++i)
        #pragma unroll
        for (int j = 0; j < 4; ++j) acc[i][j] = f32x4{0.f, 0.f, 0.f, 0.f};
    for (int k0 = 0; k0 < 512; k0 += 32) {
        __syncthreads();
        #pragma unroll
        for (int r0 = 0; r0 < 128; r0 += 64) {
            int r = sr + r0;
            *(i32x4*)(lA + r * 32 + sc) = *(const i32x4*)(A + (size_t)(m0 + r) * 512 + k0 + sc);
            f32x4 w0 = *(const f32x4*)(W + (size_t)(n0 + r) * 512 + k0 + sc);
            f32x4 w1 = *(const f32x4*)(W + (size_t)(n0 + r) * 512 + k0 + sc + 4);
            union { bf16x8 v; unsigned short u[8]; } cv;
            cv.u[0] = f2bf(w0.x); cv.u[1] = f2bf(w0.y); cv.u[2] = f2bf(w0.z); cv.u[3] = f2bf(w0.w);
            cv.u[4] = f2bf(w1.x); cv.u[5] = f2bf(w1.y); cv.u[6] = f2bf(w1.z); cv.u[7] = f2bf(w1.w);
            *(bf16x8*)(lB + r * 32 + sc) = cv.v;
        }
        __syncthreads();
        bf16x8 af[4], bfr[4];
        #pragma unroll
        for (int mi = 0; mi < 4; ++mi)
            af[mi] = *(const bf16x8*)(lA + (wm * 64 + mi * 16 + fr) * 32 + kc);
        #pragma unroll
        for (int ni = 0; ni < 4; ++ni)
            bfr[ni] = *(const bf16x8*)(lB + (wn * 64 + ni * 16 + fr) * 32 + kc);
        #pragma unroll
        for (int mi = 0; mi < 4; ++mi)
            #pragma unroll
            for (int ni = 0; ni < 4; ++ni)
                acc[mi][ni] = __builtin_amdgcn_mfma_f32_16x16x32_bf16(af[mi], bfr[ni], acc[mi][ni], 0, 0, 0);
    }
    const int orow = (lane >> 4) * 4;
    #pragma unroll
    for (int mi = 0; mi < 4; ++mi) {
        #pragma unroll
        for (int ni = 0; ni < 4; ++ni) {
            int gm = m0 + wm * 64 + mi * 16 + orow;
            int gn = n0 + wn * 64 + ni * 16 + fr;
            float bo = bout[gn];
            #pragma unroll
            for (int j = 0; j < 4; ++j)
                out[(size_t)(gm + j) * 32000 + gn] = acc[mi][ni][j] + bo;
        }
    }
}

// ---------------- row softmax in-place (LDS row buffer: 1 read + 1 write of HBM) ----------------
__global__ __launch_bounds__(512) void softmax_kernel(float* __restrict__ out) {
    __shared__ __align__(16) float row[32000];
    __shared__ float red[8];
    const int tid = threadIdx.x;
    float* p = out + (size_t)blockIdx.x * 32000;
    float mx = -3.4e38f;
    for (int c = tid; c < 8000; c += 512) {
        f32x4 v = *(const f32x4*)(p + c * 4);
        *(f32x4*)(row + c * 4) = v;
        mx = fmaxf(mx, fmaxf(fmaxf(v.x, v.y), fmaxf(v.z, v.w)));
    }
    #pragma unroll
    for (int o = 32; o; o >>= 1) mx = fmaxf(mx, __shfl_xor(mx, o, 64));
    if ((tid & 63) == 0) red[tid >> 6] = mx;
    __syncthreads();
    if (tid == 0) {
        float m = red[0];
        for (int i = 1; i < 8; ++i) m = fmaxf(m, red[i]);
        red[0] = m;
    }
    __syncthreads();
    mx = red[0];
    __syncthreads();
    float s = 0.f;
    for (int c = tid; c < 8000; c += 512) {
        f32x4 v = *(f32x4*)(row + c * 4);
        v.x = __expf(v.x - mx); v.y = __expf(v.y - mx);
        v.z = __expf(v.z - mx); v.w = __expf(v.w - mx);
        *(f32x4*)(row + c * 4) = v;
        s += v.x + v.y + v.z + v.w;
    }
    #pragma unroll
    for (int o = 32; o; o >>= 1) s += __shfl_xor(s, o, 64);
    if ((tid & 63) == 0) red[tid >> 6] = s;
    __syncthreads();
    if (tid == 0) {
        float t2 = 0.f;
        for (int i = 0; i < 8; ++i) t2 += red[i];
        red[0] = t2;
    }
    __syncthreads();
    float inv = 1.f / red[0];
    for (int c = tid; c < 8000; c += 512) {
        f32x4 v = *(f32x4*)(row + c * 4);
        v.x *= inv; v.y *= inv; v.z *= inv; v.w *= inv;
        *(f32x4*)(p + c * 4) = v;
    }
}

extern "C" void kernel_launch(void* const* d_in, const int* in_sizes, int n_in,
                              void* d_out, int out_size, void* d_ws, size_t ws_size,
                              hipStream_t stream) {
    (void)in_sizes; (void)n_in; (void)out_size; (void)ws_size;
    const float* x    = (const float*)d_in[0];
    const float* eps  = (const float*)d_in[1];
    const float* eWih = (const float*)d_in[2];
    const float* eWhh = (const float*)d_in[3];
    const float* ebih = (const float*)d_in[4];
    const float* ebhh = (const float*)d_in[5];
    const float* Wmu  = (const float*)d_in[6];
    const float* bmu  = (const float*)d_in[7];
    const float* Wlv  = (const float*)d_in[8];
    const float* blv  = (const float*)d_in[9];
    const float* dWih = (const float*)d_in[10];
    const float* dWhh = (const float*)d_in[11];
    const float* dbih = (const float*)d_in[12];
    const float* dbhh = (const float*)d_in[13];
    const float* Wout = (const float*)d_in[14];
    const float* bout = (const float*)d_in[15];
    float* out = (float*)d_out;

    // workspace layout (bytes): ~16.2 MB total
    char* ws = (char*)d_ws;
    unsigned* flags_e      = (unsigned*)ws;                       // 64*16*4 = 4 KB
    unsigned* flags_d      = (unsigned*)(ws + 4096);              // 32*16*4 = 2 KB
    unsigned short* x_bf   = (unsigned short*)(ws + 8192);        // 16*256*512*2 = 4 MB
    unsigned short* ysbf   = x_bf + (size_t)16 * 256 * 512;       // 4096*512*2 = 4 MB
    unsigned short* h_ring = ysbf + (size_t)4096 * 512;           // 256 * 16*1024 * 2B = 8 MB
    unsigned short* z_bf   = h_ring + (size_t)256 * 16 * 1024;    // 16*512*2 = 16 KB
    float* hT              = (float*)(z_bf + 16 * 512);           // 16*1024*4 = 64 KB

    hipLaunchKernelGGL(init_kernel, dim3(8), dim3(256), 0, stream, flags_e);
    hipLaunchKernelGGL(cvt_x, dim3(2048), dim3(256), 0, stream, x, x_bf);
    hipLaunchKernelGGL(enc_kernel, dim3(ENC_NB), dim3(256), 0, stream,
                       eWih, eWhh, ebih, ebhh, x_bf, h_ring, hT, flags_e);
    hipLaunchKernelGGL(mlz_kernel, dim3(32), dim3(256), 0, stream,
                       hT, Wmu, bmu, Wlv, blv, eps, z_bf, out + 131072000);
    hipLaunchKernelGGL(dec_kernel, dim3(DEC_NB), dim3(256), 0, stream,
                       dWih, dWhh, dbih, dbhh, x_bf, z_bf, ysbf, flags_d);
    hipLaunchKernelGGL(gemm_logits, dim3(8000), dim3(256), 0, stream, ysbf, Wout, bout, out);
    hipLaunchKernelGGL(softmax_kernel, dim3(4096), dim3(512), 0, stream, out);
}